// Round 16
// baseline (1041.274 us; speedup 1.0000x reference)
//
#include <hip/hip_runtime.h>
#include <hip/hip_fp16.h>

#define NN 20000
#define NE 100000
#define TSQ_NB 256

typedef _Float16 f16x8 __attribute__((ext_vector_type(8)));
typedef float f32x4 __attribute__((ext_vector_type(4)));

__device__ __forceinline__ float wred(float v) {
#pragma unroll
  for (int k = 1; k < 64; k <<= 1) v += __shfl_xor(v, k);
  return v;
}

// ========= pre0: zero workspace + fold_w1 (parallel: 10 row-blocks + bias) =========
__global__ __launch_bounds__(256) void pre0(float* __restrict__ zbase,
                                            const float* __restrict__ edge_W,
                                            const float* __restrict__ edge_b,
                                            const float* __restrict__ en_W1,
                                            const float* __restrict__ en_b1,
                                            float* __restrict__ Wc, float* __restrict__ bc) {
  int bid = blockIdx.x, t = threadIdx.x;
  if (bid < 145) {
    int i = bid * 256 + t;
    if (i < 36896) zbase[i] = 0.f;
  } else if (bid < 155) {
    int bq = bid - 145;  // 0..9
    if (t < 128) {
      float a = 0.f;
      for (int q = 0; q < 128; ++q) a += edge_W[bq * 128 + q] * en_W1[q * 128 + t];
      Wc[bq * 128 + t] = a;
    }
  } else {
    if (t < 128) {
      float a = en_b1[t];
      for (int q = 0; q < 128; ++q) a += edge_b[q] * en_W1[q * 128 + t];
      bc[t] = a;
    }
  }
}

// ==== pre1: colstats via fixed-column register accumulation + deg ====
// node: 200 blocks (stride 51200, 51200%40==0 -> col fixed per thread)
// edge: 250 blocks (stride 64000, 64000%10==0 -> col fixed per thread)
__global__ __launch_bounds__(256) void pre1(const float* __restrict__ x_node,
                                            const float* __restrict__ x_edge,
                                            const int* __restrict__ dst,
                                            float* __restrict__ nstat,
                                            float* __restrict__ estat,
                                            float* __restrict__ deg) {
  __shared__ float ls[80];
  int bid = blockIdx.x, t = threadIdx.x;
  if (bid < 200) {
    for (int i = t; i < 80; i += 256) ls[i] = 0.f;
    __syncthreads();
    int start = bid * 256 + t;
    int c = start % 40;
    float s = 0.f, sq = 0.f;
    for (int idx = start; idx < NN * 40; idx += 200 * 256) {
      float v = x_node[idx];
      s += v; sq += v * v;
    }
    atomicAdd(&ls[c], s);
    atomicAdd(&ls[40 + c], sq);
    __syncthreads();
    for (int i = t; i < 80; i += 256) atomicAdd(&nstat[i], ls[i]);
  } else if (bid < 450) {
    int b2 = bid - 200;
    for (int i = t; i < 20; i += 256) ls[i] = 0.f;
    __syncthreads();
    int start = b2 * 256 + t;
    int c = start % 10;
    float s = 0.f, sq = 0.f;
    for (int idx = start; idx < NE * 10; idx += 250 * 256) {
      float v = x_edge[idx];
      s += v; sq += v * v;
    }
    atomicAdd(&ls[c], s);
    atomicAdd(&ls[10 + c], sq);
    __syncthreads();
    for (int i = t; i < 20; i += 256) atomicAdd(&estat[i], ls[i]);
  } else {
    int e = (bid - 450) * 256 + t;
    if (e < NE) atomicAdd(&deg[dst[e]], 1.f);
  }
}

// ========= pre2: finalize_bn(node) + finalize_bn(edge) + rowptr scan =========
__global__ __launch_bounds__(256) void pre2(const float* __restrict__ nstat,
                                            const float* __restrict__ estat,
                                            const float* __restrict__ bn_n_g,
                                            const float* __restrict__ bn_n_b,
                                            const float* __restrict__ bn_e_g,
                                            const float* __restrict__ bn_e_b,
                                            float* __restrict__ ns, float* __restrict__ nc,
                                            float* __restrict__ es, float* __restrict__ ec,
                                            const float* __restrict__ deg,
                                            int* __restrict__ rowptr,
                                            int* __restrict__ cursor) {
  __shared__ int ps[256];
  int bid = blockIdx.x, t = threadIdx.x;
  if (bid == 0) {
    if (t < 40) {
      float invR = 1.f / (float)NN;
      float mean = nstat[t] * invR;
      float var = fmaxf(nstat[40 + t] * invR - mean * mean, 0.f);
      float sc = bn_n_g[t] * rsqrtf(var + 1e-5f);
      ns[t] = sc;
      nc[t] = bn_n_b[t] - mean * sc;
    }
  } else if (bid == 1) {
    if (t < 10) {
      float invR = 1.f / (float)NE;
      float mean = estat[t] * invR;
      float var = fmaxf(estat[10 + t] * invR - mean * mean, 0.f);
      float sc = bn_e_g[t] * rsqrtf(var + 1e-5f);
      es[t] = sc;
      ec[t] = bn_e_b[t] - mean * sc;
    }
  } else {
    const int CH = 79;
    int base = t * CH;
    int s = 0;
    for (int i = 0; i < CH; ++i) {
      int n = base + i;
      if (n < NN) s += (int)deg[n];
    }
    ps[t] = s;
    __syncthreads();
    for (int off = 1; off < 256; off <<= 1) {
      int v = (t >= off) ? ps[t - off] : 0;
      __syncthreads();
      ps[t] += v;
      __syncthreads();
    }
    int run = (t == 0) ? 0 : ps[t - 1];
    for (int i = 0; i < CH; ++i) {
      int n = base + i;
      if (n < NN) {
        rowptr[n] = run;
        cursor[n] = run;
        run += (int)deg[n];
      }
    }
    if (t == 255) rowptr[NN] = run;
  }
}

// ====== pre3: Sx (LDS-staged) + node embedding + dst-sort scatter ======
__global__ __launch_bounds__(256) void pre3(const float* __restrict__ x_edge,
                                            const float* __restrict__ es,
                                            const float* __restrict__ ec,
                                            float* __restrict__ sxs,
                                            const float* __restrict__ x_node,
                                            const float* __restrict__ ns,
                                            const float* __restrict__ nc,
                                            const float* __restrict__ node_W,
                                            const float* __restrict__ node_b,
                                            float* __restrict__ h_out,
                                            const int* __restrict__ src,
                                            const int* __restrict__ dst,
                                            int* __restrict__ cursor,
                                            int* __restrict__ inv_e,
                                            int* __restrict__ src_s) {
  __shared__ float xst[11][257];
  __shared__ float Wl[40 * 32];
  __shared__ float sl[40], cl[40];
  int bid = blockIdx.x, t = threadIdx.x;
  if (bid < 391) {
    if (t < 10) { sl[t] = es[t]; cl[t] = ec[t]; }
    xst[10][t] = 1.f;
    if (t == 0) xst[10][256] = 1.f;
    __syncthreads();
    int e0 = bid * 256;
    int ne = min(NE - e0, 256);
    int total = ne * 10;
    const float* xp = x_edge + (size_t)e0 * 10;
#pragma unroll
    for (int k = 0; k < 10; ++k) {
      int idx = k * 256 + t;
      if (idx < total) {
        int f = idx % 10;
        xst[f][idx / 10] = xp[idx] * sl[f] + cl[f];
      }
    }
    __syncthreads();
    if (t < 110) {
      int a = t / 11, b = t % 11;
      const float* ra = &xst[a][0];
      const float* rb = &xst[b][0];
      float acc0 = 0.f, acc1 = 0.f;
      int e = 0;
      for (; e + 1 < ne; e += 2) {
        acc0 += ra[e] * rb[e];
        acc1 += ra[e + 1] * rb[e + 1];
      }
      if (e < ne) acc0 += ra[e] * rb[e];
      atomicAdd(&sxs[(b < 10) ? (a * 10 + b) : (100 + a)], acc0 + acc1);
    }
  } else if (bid < 2891) {
    for (int i = t; i < 1280; i += 256) Wl[i] = node_W[i];
    if (t < 40) { sl[t] = ns[t]; cl[t] = nc[t]; }
    __syncthreads();
    int gid = (bid - 391) * 256 + t;
    if (gid >= NN * 32) return;
    int r = gid >> 5, j = gid & 31;
    float acc = node_b[j];
#pragma unroll
    for (int k = 0; k < 40; ++k)
      acc += (x_node[(size_t)r * 40 + k] * sl[k] + cl[k]) * Wl[k * 32 + j];
    h_out[gid] = acc;
  } else {
    int e = (bid - 2891) * 256 + t;
    if (e < NE) {
      int d = dst[e];
      int pos = atomicAdd(&cursor[d], 1);
      inv_e[e] = pos;
      src_s[pos] = src[e];
    }
  }
}

// ---- BN1 scale/shift from Sx quadratic form ----
__global__ void bn1_from_sx(const float* __restrict__ sxs, const float* __restrict__ Wc,
                            const float* __restrict__ bc, const float* __restrict__ g,
                            const float* __restrict__ b, float* __restrict__ s1,
                            float* __restrict__ c1) {
  int j = threadIdx.x;  // 128
  float w[10];
#pragma unroll
  for (int q = 0; q < 10; ++q) w[q] = Wc[q * 128 + j];
  float d = 0.f;
#pragma unroll
  for (int q = 0; q < 10; ++q) d += sxs[100 + q] * w[q];
  float qq = 0.f;
#pragma unroll
  for (int a = 0; a < 10; ++a) {
    float p = 0.f;
#pragma unroll
    for (int bq = 0; bq < 10; ++bq) p += sxs[a * 10 + bq] * w[bq];
    qq += w[a] * p;
  }
  float invE = 1.f / (float)NE;
  float bias = bc[j];
  float mean = d * invE + bias;
  float m2 = (qq + 2.f * bias * d) * invE + bias * bias;
  float var = fmaxf(m2 - mean * mean, 0.f);
  float sc = g[j] * rsqrtf(var + 1e-5f);
  s1[j] = sc;
  c1[j] = b[j] - mean * sc;
}

// ---- t_kernel: rows written at dst-sorted positions (via inv_e) ----
__global__ __launch_bounds__(256) void t_kernel(const float* __restrict__ x,
                                                const float* __restrict__ es,
                                                const float* __restrict__ ec,
                                                const float* __restrict__ Wc,
                                                const float* __restrict__ bcb,
                                                const float* __restrict__ s1,
                                                const float* __restrict__ c1,
                                                const int* __restrict__ inv_e,
                                                __half* __restrict__ T, int E) {
  __shared__ float Wcl[1280], bcl[128], s1l[128], c1l[128], esl[10], ecl[10];
  __shared__ float xr[16][10];
  int t = threadIdx.x;
  for (int i = t; i < 1280; i += 256) Wcl[i] = Wc[i];
  if (t < 128) { bcl[t] = bcb[t]; s1l[t] = s1[t]; c1l[t] = c1[t]; }
  if (t < 10) { esl[t] = es[t]; ecl[t] = ec[t]; }
  int r0 = blockIdx.x * 16;
  if (t < 160) xr[t / 10][t % 10] = x[(size_t)r0 * 10 + t];
  __syncthreads();
  int rl = t >> 4, c0 = (t & 15) * 8;
  float acc[8];
#pragma unroll
  for (int j = 0; j < 8; ++j) acc[j] = bcl[c0 + j];
#pragma unroll
  for (int q = 0; q < 10; ++q) {
    float xb = xr[rl][q] * esl[q] + ecl[q];
#pragma unroll
    for (int j = 0; j < 8; ++j) acc[j] += xb * Wcl[q * 128 + c0 + j];
  }
  f16x8 o;
#pragma unroll
  for (int j = 0; j < 8; ++j) {
    float tv = acc[j] * s1l[c0 + j] + c1l[c0 + j];
    tv = tv > 0.f ? tv : 0.8f * tv;
    o[j] = (_Float16)tv;
  }
  int rs = inv_e[r0 + rl];
  *(f16x8*)&T[(size_t)rs * 128 + c0] = o;
}

// ================= pre6: vectorized colsum(T) + MFMA S-partials =================
__global__ __launch_bounds__(256) void pre6(const __half* __restrict__ T,
                                            float* __restrict__ tsum,
                                            float* __restrict__ partial, int E) {
  __shared__ float csum[16][128];
  __shared__ _Float16 tl[32 * 132];
  int bid = blockIdx.x, t = threadIdx.x;
  if (bid < 512) {
    int rg = t >> 4;
    int cg = (t & 15) * 8;
    float a[8] = {0.f, 0.f, 0.f, 0.f, 0.f, 0.f, 0.f, 0.f};
    for (int r = bid * 16 + rg; r < E; r += 512 * 16) {
      uint4 u = *(const uint4*)&T[(size_t)r * 128 + cg];
      const __half* hp = (const __half*)&u;
#pragma unroll
      for (int q = 0; q < 8; ++q) a[q] += __half2float(hp[q]);
    }
#pragma unroll
    for (int q = 0; q < 8; ++q) csum[rg][cg + q] = a[q];
    __syncthreads();
    if (t < 128) {
      float s = 0.f;
#pragma unroll
      for (int r = 0; r < 16; ++r) s += csum[r][t];
      atomicAdd(&tsum[t], s);
    }
  } else {
    int bq = bid - 512;  // 0..255
    int w = t >> 6, lane = t & 63;
    int g = lane >> 4, cl = lane & 15;
    f32x4 acc[2][8];
#pragma unroll
    for (int i = 0; i < 2; ++i)
#pragma unroll
      for (int j = 0; j < 8; ++j) acc[i][j] = {0.f, 0.f, 0.f, 0.f};
    int nch = E >> 5;
    for (int ch = bq; ch < nch; ch += TSQ_NB) {
      __syncthreads();
#pragma unroll
      for (int p = 0; p < 4; ++p) {
        int u = p * 256 + t;
        int e = u >> 5, c0 = (u & 31) * 4;
        *(uint2*)&tl[e * 132 + c0] = *(const uint2*)&T[((size_t)ch * 32 + e) * 128 + c0];
      }
      __syncthreads();
      f16x8 fr[8];
#pragma unroll
      for (int cb = 0; cb < 8; ++cb) {
        f16x8 f;
#pragma unroll
        for (int j = 0; j < 8; ++j) f[j] = tl[(g * 8 + j) * 132 + cb * 16 + cl];
        fr[cb] = f;
      }
      f16x8 afr[2];
#pragma unroll
      for (int ri = 0; ri < 2; ++ri) {
        int cb = w * 2 + ri;
        f16x8 f;
#pragma unroll
        for (int j = 0; j < 8; ++j) f[j] = tl[(g * 8 + j) * 132 + cb * 16 + cl];
        afr[ri] = f;
      }
#pragma unroll
      for (int ri = 0; ri < 2; ++ri)
#pragma unroll
        for (int ci = 0; ci < 8; ++ci)
          acc[ri][ci] = __builtin_amdgcn_mfma_f32_16x16x32_f16(afr[ri], fr[ci], acc[ri][ci], 0, 0, 0);
    }
    float* pb = partial + (size_t)bq * 16384;
#pragma unroll
    for (int ri = 0; ri < 2; ++ri)
#pragma unroll
      for (int ci = 0; ci < 8; ++ci)
#pragma unroll
        for (int q = 0; q < 4; ++q)
          pb[(w * 32 + ri * 16 + g * 4 + q) * 128 + ci * 16 + cl] = acc[ri][ci][q];
  }
}

__global__ void tsq_reduce(const float* __restrict__ partial, float* __restrict__ S) {
  int i = blockIdx.x * 256 + threadIdx.x;  // 16384
  float a = 0.f;
  for (int b = 0; b < TSQ_NB; ++b) a += partial[(size_t)b * 16384 + i];
  S[i] = a;
}

// ---- parallel BN2 from S quadratic form ----
__global__ __launch_bounds__(256) void bn2p(const float* __restrict__ S,
                                            const float* __restrict__ tsum,
                                            const float* __restrict__ W2,
                                            const float* __restrict__ b2,
                                            const float* __restrict__ g,
                                            const float* __restrict__ b,
                                            float* __restrict__ s2, float* __restrict__ c2p) {
  __shared__ float Sl[16384];
  __shared__ float tsl[128];
  for (int i = threadIdx.x; i < 16384; i += 256) Sl[i] = S[i];
  if (threadIdx.x < 128) tsl[threadIdx.x] = tsum[threadIdx.x];
  __syncthreads();
  int w = threadIdx.x >> 6, lane = threadIdx.x & 63;
  int io = blockIdx.x * 4 + w;
  float wlo = W2[(size_t)lane * 1024 + io];
  float whi = W2[(size_t)(lane + 64) * 1024 + io];
  float plo = 0.f, phi = 0.f;
#pragma unroll
  for (int a = 0; a < 64; ++a) {
    float wa = __shfl(wlo, a);
    plo += wa * Sl[a * 128 + lane];
    phi += wa * Sl[a * 128 + lane + 64];
  }
#pragma unroll
  for (int a = 0; a < 64; ++a) {
    float wa = __shfl(whi, a);
    plo += wa * Sl[(a + 64) * 128 + lane];
    phi += wa * Sl[(a + 64) * 128 + lane + 64];
  }
  float qq = wred(plo * wlo + phi * whi);
  float d = wred(wlo * tsl[lane] + whi * tsl[lane + 64]);
  if (lane == 0) {
    float invE = 1.f / (float)NE;
    float mean_raw = d * invE;
    float var = fmaxf(qq * invE - mean_raw * mean_raw, 0.f);
    float sc = g[io] * rsqrtf(var + 1e-5f);
    s2[io] = sc;
    c2p[io] = b[io] - (mean_raw + b2[io]) * sc;
  }
}

// ================= pre9: repack W2*s2 + layer-0 hc =================
__global__ __launch_bounds__(256) void pre9(const float* __restrict__ W2,
                                            const float* __restrict__ s2,
                                            unsigned short* __restrict__ Bp,
                                            const float* __restrict__ h,
                                            const float* __restrict__ c2p,
                                            float* __restrict__ hc) {
  __shared__ float cl[1024];
  int bid = blockIdx.x, t = threadIdx.x;
  if (bid < 64) {
    int idx = bid * 256 + t;
    int cb = idx >> 8;
    int ks = (idx >> 6) & 3;
    int lane = idx & 63;
    int col = cb * 16 + (lane & 15);
    int kbase = ks * 32 + (lane >> 4) * 8;
    float sc = s2[col];
    unsigned short tmp[8];
#pragma unroll
    for (int j = 0; j < 8; ++j)
      tmp[j] = __half_as_ushort(__float2half(W2[(size_t)(kbase + j) * 1024 + col] * sc));
    *(uint4*)&Bp[(size_t)idx * 8] = *(uint4*)tmp;
  } else {
    for (int i = t; i < 1024; i += 256) cl[i] = c2p[i];
    __syncthreads();
    int gid = (bid - 64) * 256 + t;
    if (gid >= NN * 32) return;
    int n = gid >> 5, o = gid & 31;
    float a = 0.f;
#pragma unroll
    for (int i = 0; i < 32; ++i) a += h[(size_t)n * 32 + i] * cl[i * 32 + o];
    hc[gid] = a;
  }
}

// ---- FUSED msg v8: 64 edges/block (Bp reads amortized 2x), (256,3) ----
__global__ __launch_bounds__(256, 3) void msg_mfma(const __half* __restrict__ T,
                                                   const unsigned short* __restrict__ Bp,
                                                   const float* __restrict__ h,
                                                   const float* __restrict__ hc,
                                                   const int* __restrict__ src_s,
                                                   float* __restrict__ msg_buf, int E) {
  __shared__ float hst[32 * 68];     // hst[i*68 + row], rows 0..63
  __shared__ float msw[4 * 2080];    // per-wave partials: [w][o*65 + row]
  int t = threadIdx.x;
  int w = t >> 6, lane = t & 63;
  int arow = lane & 15, kgrp = lane >> 4;
  int e0 = blockIdx.x * 64;
  // ---- stage h[src] transposed: row = t>>2 (0..63), i0 = (t&3)*8 ----
  {
    int row = t >> 2, i0 = (t & 3) * 8;
    int e = e0 + row;
    int sn = (e < E) ? src_s[e] : 0;
    float4 h0 = *(const float4*)&h[(size_t)sn * 32 + i0];
    float4 h1 = *(const float4*)&h[(size_t)sn * 32 + i0 + 4];
    hst[(i0 + 0) * 68 + row] = h0.x; hst[(i0 + 1) * 68 + row] = h0.y;
    hst[(i0 + 2) * 68 + row] = h0.z; hst[(i0 + 3) * 68 + row] = h0.w;
    hst[(i0 + 4) * 68 + row] = h1.x; hst[(i0 + 5) * 68 + row] = h1.y;
    hst[(i0 + 6) * 68 + row] = h1.z; hst[(i0 + 7) * 68 + row] = h1.w;
  }
  __syncthreads();
  f32x4 pm[2][4];
#pragma unroll
  for (int p = 0; p < 2; ++p)
#pragma unroll
    for (int ri = 0; ri < 4; ++ri) pm[p][ri] = {0.f, 0.f, 0.f, 0.f};
#pragma unroll
  for (int cb = 0; cb < 4; ++cb) {
    f32x4 acc[4][4];
#pragma unroll
    for (int i = 0; i < 4; ++i)
#pragma unroll
      for (int j = 0; j < 4; ++j) acc[i][j] = {0.f, 0.f, 0.f, 0.f};
#pragma unroll
    for (int ks = 0; ks < 4; ++ks) {
      f16x8 a0, a1, a2, a3;
      {
        int r0 = e0 + arow;
        a0 = (r0 < E) ? *(const f16x8*)&T[(size_t)r0 * 128 + ks * 32 + kgrp * 8] : f16x8{};
        int r1 = r0 + 16;
        a1 = (r1 < E) ? *(const f16x8*)&T[(size_t)r1 * 128 + ks * 32 + kgrp * 8] : f16x8{};
        int r2 = r0 + 32;
        a2 = (r2 < E) ? *(const f16x8*)&T[(size_t)r2 * 128 + ks * 32 + kgrp * 8] : f16x8{};
        int r3 = r0 + 48;
        a3 = (r3 < E) ? *(const f16x8*)&T[(size_t)r3 * 128 + ks * 32 + kgrp * 8] : f16x8{};
      }
#pragma unroll
      for (int ci = 0; ci < 4; ++ci) {
        int f = cb * 16 + w * 4 + ci;
        f16x8 bv = *(const f16x8*)&Bp[((size_t)(f * 4 + ks) * 64 + lane) * 8];
        acc[0][ci] = __builtin_amdgcn_mfma_f32_16x16x32_f16(a0, bv, acc[0][ci], 0, 0, 0);
        acc[1][ci] = __builtin_amdgcn_mfma_f32_16x16x32_f16(a1, bv, acc[1][ci], 0, 0, 0);
        acc[2][ci] = __builtin_amdgcn_mfma_f32_16x16x32_f16(a2, bv, acc[2][ci], 0, 0, 0);
        acc[3][ci] = __builtin_amdgcn_mfma_f32_16x16x32_f16(a3, bv, acc[3][ci], 0, 0, 0);
      }
    }
#pragma unroll
    for (int ci = 0; ci < 4; ++ci) {
      int i = cb * 8 + w * 2 + (ci >> 1);
#pragma unroll
      for (int ri = 0; ri < 4; ++ri) {
        f32x4 hv = *(const f32x4*)&hst[i * 68 + ri * 16 + kgrp * 4];
        if (ci & 1) pm[1][ri] += hv * acc[ri][ci];
        else        pm[0][ri] += hv * acc[ri][ci];
      }
    }
  }
  {
    float* mw = &msw[w * 2080];
#pragma unroll
    for (int p = 0; p < 2; ++p) {
      int o = p * 16 + arow;
#pragma unroll
      for (int ri = 0; ri < 4; ++ri) {
        int rb = ri * 16 + kgrp * 4;
        mw[o * 65 + rb + 0] = pm[p][ri][0];
        mw[o * 65 + rb + 1] = pm[p][ri][1];
        mw[o * 65 + rb + 2] = pm[p][ri][2];
        mw[o * 65 + rb + 3] = pm[p][ri][3];
      }
    }
  }
  __syncthreads();
  {
    int row = t >> 2, o0 = (t & 3) * 8;
    int e = e0 + row;
    if (e < E) {
      int sn = src_s[e];
      const float* hcp = hc + (size_t)sn * 32;
      float vs[8];
#pragma unroll
      for (int j = 0; j < 8; ++j) {
        int o = o0 + j;
        vs[j] = msw[0 * 2080 + o * 65 + row] + msw[1 * 2080 + o * 65 + row] +
                msw[2 * 2080 + o * 65 + row] + msw[3 * 2080 + o * 65 + row] + hcp[o];
      }
      *(float4*)&msg_buf[(size_t)e * 32 + o0] = make_float4(vs[0], vs[1], vs[2], vs[3]);
      *(float4*)&msg_buf[(size_t)e * 32 + o0 + 4] = make_float4(vs[4], vs[5], vs[6], vs[7]);
    }
  }
}

// ---- GRU cell with CSR gather of sorted msgs; fused next-layer hc ----
__global__ __launch_bounds__(256) void gru_kernel(const float* __restrict__ msg_buf,
                                                  const int* __restrict__ rowptr,
                                                  const float* __restrict__ h_in,
                                                  const float* __restrict__ Wih,
                                                  const float* __restrict__ Whh,
                                                  const float* __restrict__ bih,
                                                  const float* __restrict__ bhh,
                                                  float* __restrict__ h_out,
                                                  const float* __restrict__ c2p,
                                                  float* __restrict__ hc_out,
                                                  int do_next, int N) {
  __shared__ float WT[32 * 96], UT[32 * 96];
  __shared__ float c2l[1024];
  __shared__ float mrow[256];
  __shared__ float hnew[256];
  int t = threadIdx.x;
  for (int idx = t; idx < 96 * 32; idx += 256) {
    int j = idx / 32, i = idx % 32;
    WT[i * 96 + j] = Wih[idx];
    UT[i * 96 + j] = Whh[idx];
  }
  if (do_next)
    for (int i = t; i < 1024; i += 256) c2l[i] = c2p[i];
  __syncthreads();
  int gid = blockIdx.x * 256 + t;
  int n = gid >> 5, o = gid & 31;
  int k0 = rowptr[n], k1 = rowptr[n + 1];
  float msum = 0.f;
  for (int k = k0; k < k1; ++k) msum += msg_buf[(size_t)k * 32 + o];
  float inv = 1.f / fmaxf((float)(k1 - k0), 1.f);
  mrow[t] = msum * inv;
  __syncthreads();
  int nl = t >> 5;
  float air = 0.f, aiz = 0.f, ain = 0.f, ahr = 0.f, ahz = 0.f, ahn = 0.f;
#pragma unroll
  for (int i = 0; i < 32; ++i) {
    float mi = mrow[nl * 32 + i];
    float hi = h_in[(size_t)n * 32 + i];
    const float* w = &WT[i * 96 + o];
    const float* u = &UT[i * 96 + o];
    air += mi * w[0];  aiz += mi * w[32];  ain += mi * w[64];
    ahr += hi * u[0];  ahz += hi * u[32];  ahn += hi * u[64];
  }
  float r = 1.f / (1.f + expf(-(air + bih[o] + ahr + bhh[o])));
  float z = 1.f / (1.f + expf(-(aiz + bih[o + 32] + ahz + bhh[o + 32])));
  float ng = tanhf(ain + bih[o + 64] + r * (ahn + bhh[o + 64]));
  float hval = (1.f - z) * ng + z * h_in[(size_t)n * 32 + o];
  h_out[gid] = hval;
  if (do_next) {
    hnew[t] = hval;
    __syncthreads();
    float a = 0.f;
#pragma unroll
    for (int i = 0; i < 32; ++i) a += hnew[nl * 32 + i] * c2l[i * 32 + o];
    hc_out[gid] = a;
  }
}

extern "C" void kernel_launch(void* const* d_in, const int* in_sizes, int n_in,
                              void* d_out, int out_size, void* d_ws, size_t ws_size,
                              hipStream_t stream) {
  const float* x_node = (const float*)d_in[0];
  const float* x_edge = (const float*)d_in[1];
  const int* src = (const int*)d_in[2];
  const int* dst = (const int*)d_in[3];
  const float* bn_n_g = (const float*)d_in[4];
  const float* bn_n_b = (const float*)d_in[5];
  const float* node_W = (const float*)d_in[6];
  const float* node_b = (const float*)d_in[7];
  const float* bn_e_g = (const float*)d_in[8];
  const float* bn_e_b = (const float*)d_in[9];
  const float* edge_W = (const float*)d_in[10];
  const float* edge_b = (const float*)d_in[11];
  const float* en_W1 = (const float*)d_in[12];
  const float* en_b1 = (const float*)d_in[13];
  const float* en_bn1_g = (const float*)d_in[14];
  const float* en_bn1_b = (const float*)d_in[15];
  const float* en_W2 = (const float*)d_in[16];
  const float* en_b2 = (const float*)d_in[17];
  const float* en_bn2_g = (const float*)d_in[18];
  const float* en_bn2_b = (const float*)d_in[19];
  const float* gWih = (const float*)d_in[20];
  const float* gWhh = (const float*)d_in[21];
  const float* gbih = (const float*)d_in[22];
  const float* gbhh = (const float*)d_in[23];
  float* out = (float*)d_out;

  char* ws = (char*)d_ws;
  __half* Tt      = (__half*)(ws + 0);              // 25,600,000 (dst-sorted rows)
  float* tsq_part = (float*)(ws + 25600000);        // 16,777,216
  float* h_a      = (float*)(ws + 42377216);        //  2,560,000
  float* h_b      = (float*)(ws + 44937216);        //  2,560,000
  float* msg_buf  = (float*)(ws + 47497216);        // 12,800,000
  float* hc       = (float*)(ws + 60297216);        //  2,560,000
  int*   src_s    = (int*)(ws + 62857216);          //    400,000
  int*   inv_e    = (int*)(ws + 63257216);          //    400,000
  int*   rowptr   = (int*)(ws + 63657216);          //     80,064
  int*   cursor   = (int*)(ws + 63737280);          //     80,000
  float* zbase    = (float*)(ws + 63817280);        //    147,584 (36,896 f)
  float* deg   = zbase;                             // 20000
  float* S     = zbase + 20000;                     // 16384
  float* tsum  = zbase + 36384;                     // 128
  float* sxs   = zbase + 36512;
  float* nstat = zbase + 36640;
  float* estat = zbase + 36768;
  float* par   = (float*)(ws + 63964864);           // 4096 f
  float* ns = par + 0;    float* nc = par + 64;
  float* es = par + 128;  float* ec = par + 192;
  float* s1 = par + 256;  float* c1 = par + 384;
  float* wc = par + 512;                            // 1280 f
  float* bcb = par + 1792;                          // 128 f
  float* s2 = par + 1920; float* c2p = par + 2944;  // 1024 f each
  unsigned short* Bp = (unsigned short*)(ws + 63981248);  // 262,144 B

  pre0<<<156, 256, 0, stream>>>(zbase, edge_W, edge_b, en_W1, en_b1, wc, bcb);
  pre1<<<450 + 391, 256, 0, stream>>>(x_node, x_edge, dst, nstat, estat, deg);
  pre2<<<3, 256, 0, stream>>>(nstat, estat, bn_n_g, bn_n_b, bn_e_g, bn_e_b,
                              ns, nc, es, ec, deg, rowptr, cursor);
  pre3<<<391 + 2500 + 391, 256, 0, stream>>>(x_edge, es, ec, sxs, x_node, ns, nc,
                                             node_W, node_b, h_a, src, dst,
                                             cursor, inv_e, src_s);
  bn1_from_sx<<<1, 128, 0, stream>>>(sxs, wc, bcb, en_bn1_g, en_bn1_b, s1, c1);
  t_kernel<<<NE / 16, 256, 0, stream>>>(x_edge, es, ec, wc, bcb, s1, c1, inv_e, Tt, NE);
  pre6<<<512 + TSQ_NB, 256, 0, stream>>>(Tt, tsum, tsq_part, NE);
  tsq_reduce<<<64, 256, 0, stream>>>(tsq_part, S);
  bn2p<<<256, 256, 0, stream>>>(S, tsum, en_W2, en_b2, en_bn2_g, en_bn2_b, s2, c2p);
  pre9<<<64 + 2500, 256, 0, stream>>>(en_W2, s2, Bp, h_a, c2p, hc);

  const float* hin = h_a;
  for (int l = 0; l < 3; ++l) {
    float* hout = (l == 0) ? h_b : (l == 1) ? h_a : out;
    msg_mfma<<<(NE + 63) / 64, 256, 0, stream>>>(Tt, Bp, hin, hc, src_s, msg_buf, NE);
    gru_kernel<<<(NN * 32) / 256, 256, 0, stream>>>(msg_buf, rowptr, hin, gWih, gWhh,
                                                    gbih, gbhh, hout, c2p, hc,
                                                    (l < 2) ? 1 : 0, NN);
    hin = hout;
  }
}

// Round 17
// 527.603 us; speedup vs baseline: 1.9736x; 1.9736x over previous
//
#include <hip/hip_runtime.h>
#include <hip/hip_fp16.h>

#define NN 20000
#define NE 100000
#define TSQ_NB 256

typedef _Float16 f16x8 __attribute__((ext_vector_type(8)));
typedef float f32x4 __attribute__((ext_vector_type(4)));

__device__ __forceinline__ float wred(float v) {
#pragma unroll
  for (int k = 1; k < 64; k <<= 1) v += __shfl_xor(v, k);
  return v;
}

// ========= pre0: zero workspace + fold_w1 (parallel: 10 row-blocks + bias) =========
__global__ __launch_bounds__(256) void pre0(float* __restrict__ zbase,
                                            const float* __restrict__ edge_W,
                                            const float* __restrict__ edge_b,
                                            const float* __restrict__ en_W1,
                                            const float* __restrict__ en_b1,
                                            float* __restrict__ Wc, float* __restrict__ bc) {
  int bid = blockIdx.x, t = threadIdx.x;
  if (bid < 145) {
    int i = bid * 256 + t;
    if (i < 36896) zbase[i] = 0.f;
  } else if (bid < 155) {
    int bq = bid - 145;  // 0..9
    if (t < 128) {
      float a = 0.f;
      for (int q = 0; q < 128; ++q) a += edge_W[bq * 128 + q] * en_W1[q * 128 + t];
      Wc[bq * 128 + t] = a;
    }
  } else {
    if (t < 128) {
      float a = en_b1[t];
      for (int q = 0; q < 128; ++q) a += edge_b[q] * en_W1[q * 128 + t];
      bc[t] = a;
    }
  }
}

// ==== pre1: colstats via fixed-column register accumulation + deg ====
__global__ __launch_bounds__(256) void pre1(const float* __restrict__ x_node,
                                            const float* __restrict__ x_edge,
                                            const int* __restrict__ dst,
                                            float* __restrict__ nstat,
                                            float* __restrict__ estat,
                                            float* __restrict__ deg) {
  __shared__ float ls[80];
  int bid = blockIdx.x, t = threadIdx.x;
  if (bid < 200) {
    for (int i = t; i < 80; i += 256) ls[i] = 0.f;
    __syncthreads();
    int start = bid * 256 + t;
    int c = start % 40;
    float s = 0.f, sq = 0.f;
    for (int idx = start; idx < NN * 40; idx += 200 * 256) {
      float v = x_node[idx];
      s += v; sq += v * v;
    }
    atomicAdd(&ls[c], s);
    atomicAdd(&ls[40 + c], sq);
    __syncthreads();
    for (int i = t; i < 80; i += 256) atomicAdd(&nstat[i], ls[i]);
  } else if (bid < 450) {
    int b2 = bid - 200;
    for (int i = t; i < 20; i += 256) ls[i] = 0.f;
    __syncthreads();
    int start = b2 * 256 + t;
    int c = start % 10;
    float s = 0.f, sq = 0.f;
    for (int idx = start; idx < NE * 10; idx += 250 * 256) {
      float v = x_edge[idx];
      s += v; sq += v * v;
    }
    atomicAdd(&ls[c], s);
    atomicAdd(&ls[10 + c], sq);
    __syncthreads();
    for (int i = t; i < 20; i += 256) atomicAdd(&estat[i], ls[i]);
  } else {
    int e = (bid - 450) * 256 + t;
    if (e < NE) atomicAdd(&deg[dst[e]], 1.f);
  }
}

// ========= pre2: finalize_bn(node) + finalize_bn(edge) + rowptr scan =========
__global__ __launch_bounds__(256) void pre2(const float* __restrict__ nstat,
                                            const float* __restrict__ estat,
                                            const float* __restrict__ bn_n_g,
                                            const float* __restrict__ bn_n_b,
                                            const float* __restrict__ bn_e_g,
                                            const float* __restrict__ bn_e_b,
                                            float* __restrict__ ns, float* __restrict__ nc,
                                            float* __restrict__ es, float* __restrict__ ec,
                                            const float* __restrict__ deg,
                                            int* __restrict__ rowptr,
                                            int* __restrict__ cursor) {
  __shared__ int ps[256];
  int bid = blockIdx.x, t = threadIdx.x;
  if (bid == 0) {
    if (t < 40) {
      float invR = 1.f / (float)NN;
      float mean = nstat[t] * invR;
      float var = fmaxf(nstat[40 + t] * invR - mean * mean, 0.f);
      float sc = bn_n_g[t] * rsqrtf(var + 1e-5f);
      ns[t] = sc;
      nc[t] = bn_n_b[t] - mean * sc;
    }
  } else if (bid == 1) {
    if (t < 10) {
      float invR = 1.f / (float)NE;
      float mean = estat[t] * invR;
      float var = fmaxf(estat[10 + t] * invR - mean * mean, 0.f);
      float sc = bn_e_g[t] * rsqrtf(var + 1e-5f);
      es[t] = sc;
      ec[t] = bn_e_b[t] - mean * sc;
    }
  } else {
    const int CH = 79;
    int base = t * CH;
    int s = 0;
    for (int i = 0; i < CH; ++i) {
      int n = base + i;
      if (n < NN) s += (int)deg[n];
    }
    ps[t] = s;
    __syncthreads();
    for (int off = 1; off < 256; off <<= 1) {
      int v = (t >= off) ? ps[t - off] : 0;
      __syncthreads();
      ps[t] += v;
      __syncthreads();
    }
    int run = (t == 0) ? 0 : ps[t - 1];
    for (int i = 0; i < CH; ++i) {
      int n = base + i;
      if (n < NN) {
        rowptr[n] = run;
        cursor[n] = run;
        run += (int)deg[n];
      }
    }
    if (t == 255) rowptr[NN] = run;
  }
}

// ====== pre3: Sx (LDS-staged) + node embedding + dst-sort scatter ======
__global__ __launch_bounds__(256) void pre3(const float* __restrict__ x_edge,
                                            const float* __restrict__ es,
                                            const float* __restrict__ ec,
                                            float* __restrict__ sxs,
                                            const float* __restrict__ x_node,
                                            const float* __restrict__ ns,
                                            const float* __restrict__ nc,
                                            const float* __restrict__ node_W,
                                            const float* __restrict__ node_b,
                                            float* __restrict__ h_out,
                                            const int* __restrict__ src,
                                            const int* __restrict__ dst,
                                            int* __restrict__ cursor,
                                            int* __restrict__ inv_e,
                                            int* __restrict__ src_s) {
  __shared__ float xst[11][257];
  __shared__ float Wl[40 * 32];
  __shared__ float sl[40], cl[40];
  int bid = blockIdx.x, t = threadIdx.x;
  if (bid < 391) {
    if (t < 10) { sl[t] = es[t]; cl[t] = ec[t]; }
    xst[10][t] = 1.f;
    if (t == 0) xst[10][256] = 1.f;
    __syncthreads();
    int e0 = bid * 256;
    int ne = min(NE - e0, 256);
    int total = ne * 10;
    const float* xp = x_edge + (size_t)e0 * 10;
#pragma unroll
    for (int k = 0; k < 10; ++k) {
      int idx = k * 256 + t;
      if (idx < total) {
        int f = idx % 10;
        xst[f][idx / 10] = xp[idx] * sl[f] + cl[f];
      }
    }
    __syncthreads();
    if (t < 110) {
      int a = t / 11, b = t % 11;
      const float* ra = &xst[a][0];
      const float* rb = &xst[b][0];
      float acc0 = 0.f, acc1 = 0.f;
      int e = 0;
      for (; e + 1 < ne; e += 2) {
        acc0 += ra[e] * rb[e];
        acc1 += ra[e + 1] * rb[e + 1];
      }
      if (e < ne) acc0 += ra[e] * rb[e];
      atomicAdd(&sxs[(b < 10) ? (a * 10 + b) : (100 + a)], acc0 + acc1);
    }
  } else if (bid < 2891) {
    for (int i = t; i < 1280; i += 256) Wl[i] = node_W[i];
    if (t < 40) { sl[t] = ns[t]; cl[t] = nc[t]; }
    __syncthreads();
    int gid = (bid - 391) * 256 + t;
    if (gid >= NN * 32) return;
    int r = gid >> 5, j = gid & 31;
    float acc = node_b[j];
#pragma unroll
    for (int k = 0; k < 40; ++k)
      acc += (x_node[(size_t)r * 40 + k] * sl[k] + cl[k]) * Wl[k * 32 + j];
    h_out[gid] = acc;
  } else {
    int e = (bid - 2891) * 256 + t;
    if (e < NE) {
      int d = dst[e];
      int pos = atomicAdd(&cursor[d], 1);
      inv_e[e] = pos;
      src_s[pos] = src[e];
    }
  }
}

// ---- BN1 scale/shift from Sx quadratic form ----
__global__ void bn1_from_sx(const float* __restrict__ sxs, const float* __restrict__ Wc,
                            const float* __restrict__ bc, const float* __restrict__ g,
                            const float* __restrict__ b, float* __restrict__ s1,
                            float* __restrict__ c1) {
  int j = threadIdx.x;  // 128
  float w[10];
#pragma unroll
  for (int q = 0; q < 10; ++q) w[q] = Wc[q * 128 + j];
  float d = 0.f;
#pragma unroll
  for (int q = 0; q < 10; ++q) d += sxs[100 + q] * w[q];
  float qq = 0.f;
#pragma unroll
  for (int a = 0; a < 10; ++a) {
    float p = 0.f;
#pragma unroll
    for (int bq = 0; bq < 10; ++bq) p += sxs[a * 10 + bq] * w[bq];
    qq += w[a] * p;
  }
  float invE = 1.f / (float)NE;
  float bias = bc[j];
  float mean = d * invE + bias;
  float m2 = (qq + 2.f * bias * d) * invE + bias * bias;
  float var = fmaxf(m2 - mean * mean, 0.f);
  float sc = g[j] * rsqrtf(var + 1e-5f);
  s1[j] = sc;
  c1[j] = b[j] - mean * sc;
}

// ---- t_kernel: rows written at dst-sorted positions (via inv_e) ----
__global__ __launch_bounds__(256) void t_kernel(const float* __restrict__ x,
                                                const float* __restrict__ es,
                                                const float* __restrict__ ec,
                                                const float* __restrict__ Wc,
                                                const float* __restrict__ bcb,
                                                const float* __restrict__ s1,
                                                const float* __restrict__ c1,
                                                const int* __restrict__ inv_e,
                                                __half* __restrict__ T, int E) {
  __shared__ float Wcl[1280], bcl[128], s1l[128], c1l[128], esl[10], ecl[10];
  __shared__ float xr[16][10];
  int t = threadIdx.x;
  for (int i = t; i < 1280; i += 256) Wcl[i] = Wc[i];
  if (t < 128) { bcl[t] = bcb[t]; s1l[t] = s1[t]; c1l[t] = c1[t]; }
  if (t < 10) { esl[t] = es[t]; ecl[t] = ec[t]; }
  int r0 = blockIdx.x * 16;
  if (t < 160) xr[t / 10][t % 10] = x[(size_t)r0 * 10 + t];
  __syncthreads();
  int rl = t >> 4, c0 = (t & 15) * 8;
  float acc[8];
#pragma unroll
  for (int j = 0; j < 8; ++j) acc[j] = bcl[c0 + j];
#pragma unroll
  for (int q = 0; q < 10; ++q) {
    float xb = xr[rl][q] * esl[q] + ecl[q];
#pragma unroll
    for (int j = 0; j < 8; ++j) acc[j] += xb * Wcl[q * 128 + c0 + j];
  }
  f16x8 o;
#pragma unroll
  for (int j = 0; j < 8; ++j) {
    float tv = acc[j] * s1l[c0 + j] + c1l[c0 + j];
    tv = tv > 0.f ? tv : 0.8f * tv;
    o[j] = (_Float16)tv;
  }
  int rs = inv_e[r0 + rl];
  *(f16x8*)&T[(size_t)rs * 128 + c0] = o;
}

// ================= pre6: vectorized colsum(T) + MFMA S-partials =================
__global__ __launch_bounds__(256) void pre6(const __half* __restrict__ T,
                                            float* __restrict__ tsum,
                                            float* __restrict__ partial, int E) {
  __shared__ float csum[16][128];
  __shared__ _Float16 tl[32 * 132];
  int bid = blockIdx.x, t = threadIdx.x;
  if (bid < 512) {
    int rg = t >> 4;
    int cg = (t & 15) * 8;
    float a[8] = {0.f, 0.f, 0.f, 0.f, 0.f, 0.f, 0.f, 0.f};
    for (int r = bid * 16 + rg; r < E; r += 512 * 16) {
      uint4 u = *(const uint4*)&T[(size_t)r * 128 + cg];
      const __half* hp = (const __half*)&u;
#pragma unroll
      for (int q = 0; q < 8; ++q) a[q] += __half2float(hp[q]);
    }
#pragma unroll
    for (int q = 0; q < 8; ++q) csum[rg][cg + q] = a[q];
    __syncthreads();
    if (t < 128) {
      float s = 0.f;
#pragma unroll
      for (int r = 0; r < 16; ++r) s += csum[r][t];
      atomicAdd(&tsum[t], s);
    }
  } else {
    int bq = bid - 512;  // 0..255
    int w = t >> 6, lane = t & 63;
    int g = lane >> 4, cl = lane & 15;
    f32x4 acc[2][8];
#pragma unroll
    for (int i = 0; i < 2; ++i)
#pragma unroll
      for (int j = 0; j < 8; ++j) acc[i][j] = {0.f, 0.f, 0.f, 0.f};
    int nch = E >> 5;
    for (int ch = bq; ch < nch; ch += TSQ_NB) {
      __syncthreads();
#pragma unroll
      for (int p = 0; p < 4; ++p) {
        int u = p * 256 + t;
        int e = u >> 5, c0 = (u & 31) * 4;
        *(uint2*)&tl[e * 132 + c0] = *(const uint2*)&T[((size_t)ch * 32 + e) * 128 + c0];
      }
      __syncthreads();
      f16x8 fr[8];
#pragma unroll
      for (int cb = 0; cb < 8; ++cb) {
        f16x8 f;
#pragma unroll
        for (int j = 0; j < 8; ++j) f[j] = tl[(g * 8 + j) * 132 + cb * 16 + cl];
        fr[cb] = f;
      }
      f16x8 afr[2];
#pragma unroll
      for (int ri = 0; ri < 2; ++ri) {
        int cb = w * 2 + ri;
        f16x8 f;
#pragma unroll
        for (int j = 0; j < 8; ++j) f[j] = tl[(g * 8 + j) * 132 + cb * 16 + cl];
        afr[ri] = f;
      }
#pragma unroll
      for (int ri = 0; ri < 2; ++ri)
#pragma unroll
        for (int ci = 0; ci < 8; ++ci)
          acc[ri][ci] = __builtin_amdgcn_mfma_f32_16x16x32_f16(afr[ri], fr[ci], acc[ri][ci], 0, 0, 0);
    }
    float* pb = partial + (size_t)bq * 16384;
#pragma unroll
    for (int ri = 0; ri < 2; ++ri)
#pragma unroll
      for (int ci = 0; ci < 8; ++ci)
#pragma unroll
        for (int q = 0; q < 4; ++q)
          pb[(w * 32 + ri * 16 + g * 4 + q) * 128 + ci * 16 + cl] = acc[ri][ci][q];
  }
}

__global__ void tsq_reduce(const float* __restrict__ partial, float* __restrict__ S) {
  int i = blockIdx.x * 256 + threadIdx.x;  // 16384
  float a = 0.f;
  for (int b = 0; b < TSQ_NB; ++b) a += partial[(size_t)b * 16384 + i];
  S[i] = a;
}

// ---- parallel BN2 from S quadratic form ----
__global__ __launch_bounds__(256) void bn2p(const float* __restrict__ S,
                                            const float* __restrict__ tsum,
                                            const float* __restrict__ W2,
                                            const float* __restrict__ b2,
                                            const float* __restrict__ g,
                                            const float* __restrict__ b,
                                            float* __restrict__ s2, float* __restrict__ c2p) {
  __shared__ float Sl[16384];
  __shared__ float tsl[128];
  for (int i = threadIdx.x; i < 16384; i += 256) Sl[i] = S[i];
  if (threadIdx.x < 128) tsl[threadIdx.x] = tsum[threadIdx.x];
  __syncthreads();
  int w = threadIdx.x >> 6, lane = threadIdx.x & 63;
  int io = blockIdx.x * 4 + w;
  float wlo = W2[(size_t)lane * 1024 + io];
  float whi = W2[(size_t)(lane + 64) * 1024 + io];
  float plo = 0.f, phi = 0.f;
#pragma unroll
  for (int a = 0; a < 64; ++a) {
    float wa = __shfl(wlo, a);
    plo += wa * Sl[a * 128 + lane];
    phi += wa * Sl[a * 128 + lane + 64];
  }
#pragma unroll
  for (int a = 0; a < 64; ++a) {
    float wa = __shfl(whi, a);
    plo += wa * Sl[(a + 64) * 128 + lane];
    phi += wa * Sl[(a + 64) * 128 + lane + 64];
  }
  float qq = wred(plo * wlo + phi * whi);
  float d = wred(wlo * tsl[lane] + whi * tsl[lane + 64]);
  if (lane == 0) {
    float invE = 1.f / (float)NE;
    float mean_raw = d * invE;
    float var = fmaxf(qq * invE - mean_raw * mean_raw, 0.f);
    float sc = g[io] * rsqrtf(var + 1e-5f);
    s2[io] = sc;
    c2p[io] = b[io] - (mean_raw + b2[io]) * sc;
  }
}

// ================= pre9: repack W2*s2 + layer-0 hc =================
__global__ __launch_bounds__(256) void pre9(const float* __restrict__ W2,
                                            const float* __restrict__ s2,
                                            unsigned short* __restrict__ Bp,
                                            const float* __restrict__ h,
                                            const float* __restrict__ c2p,
                                            float* __restrict__ hc) {
  __shared__ float cl[1024];
  int bid = blockIdx.x, t = threadIdx.x;
  if (bid < 64) {
    int idx = bid * 256 + t;
    int cb = idx >> 8;
    int ks = (idx >> 6) & 3;
    int lane = idx & 63;
    int col = cb * 16 + (lane & 15);
    int kbase = ks * 32 + (lane >> 4) * 8;
    float sc = s2[col];
    unsigned short tmp[8];
#pragma unroll
    for (int j = 0; j < 8; ++j)
      tmp[j] = __half_as_ushort(__float2half(W2[(size_t)(kbase + j) * 1024 + col] * sc));
    *(uint4*)&Bp[(size_t)idx * 8] = *(uint4*)tmp;
  } else {
    for (int i = t; i < 1024; i += 256) cl[i] = c2p[i];
    __syncthreads();
    int gid = (bid - 64) * 256 + t;
    if (gid >= NN * 32) return;
    int n = gid >> 5, o = gid & 31;
    float a = 0.f;
#pragma unroll
    for (int i = 0; i < 32; ++i) a += h[(size_t)n * 32 + i] * cl[i * 32 + o];
    hc[gid] = a;
  }
}

// ---- FUSED msg (r13/r15-proven): 32 edges/block, ah hoisted, (256,3) ----
__global__ __launch_bounds__(256, 3) void msg_mfma(const __half* __restrict__ T,
                                                   const unsigned short* __restrict__ Bp,
                                                   const float* __restrict__ h,
                                                   const float* __restrict__ hc,
                                                   const int* __restrict__ src_s,
                                                   float* __restrict__ msg_buf, int E) {
  __shared__ float hst[32 * 36];     // hst[i*36 + row]
  __shared__ float msw[4 * 1056];    // per-wave partials: [w][o*33 + row]
  int t = threadIdx.x;
  int w = t >> 6, lane = t & 63;
  int arow = lane & 15, kgrp = lane >> 4;
  int e0 = blockIdx.x * 32;
  {
    int row = t >> 3, i0 = (t & 7) * 4;
    int sn = src_s[e0 + row];
    float4 hv = *(const float4*)&h[(size_t)sn * 32 + i0];
    hst[(i0 + 0) * 36 + row] = hv.x;
    hst[(i0 + 1) * 36 + row] = hv.y;
    hst[(i0 + 2) * 36 + row] = hv.z;
    hst[(i0 + 3) * 36 + row] = hv.w;
  }
  __syncthreads();
  f16x8 ah[4][2];
#pragma unroll
  for (int ks = 0; ks < 4; ++ks)
#pragma unroll
    for (int ri = 0; ri < 2; ++ri)
      ah[ks][ri] = *(const f16x8*)&T[(size_t)(e0 + ri * 16 + arow) * 128 + ks * 32 + kgrp * 8];
  f32x4 pm[2][2];
#pragma unroll
  for (int p = 0; p < 2; ++p)
#pragma unroll
    for (int ri = 0; ri < 2; ++ri) pm[p][ri] = {0.f, 0.f, 0.f, 0.f};
#pragma unroll
  for (int cb = 0; cb < 4; ++cb) {
    f32x4 acc[2][4];
#pragma unroll
    for (int i = 0; i < 2; ++i)
#pragma unroll
      for (int j = 0; j < 4; ++j) acc[i][j] = {0.f, 0.f, 0.f, 0.f};
#pragma unroll
    for (int ks = 0; ks < 4; ++ks) {
#pragma unroll
      for (int ci = 0; ci < 4; ++ci) {
        int f = cb * 16 + w * 4 + ci;
        f16x8 bv = *(const f16x8*)&Bp[((size_t)(f * 4 + ks) * 64 + lane) * 8];
        acc[0][ci] = __builtin_amdgcn_mfma_f32_16x16x32_f16(ah[ks][0], bv, acc[0][ci], 0, 0, 0);
        acc[1][ci] = __builtin_amdgcn_mfma_f32_16x16x32_f16(ah[ks][1], bv, acc[1][ci], 0, 0, 0);
      }
    }
#pragma unroll
    for (int ci = 0; ci < 4; ++ci) {
      int i = cb * 8 + w * 2 + (ci >> 1);
#pragma unroll
      for (int ri = 0; ri < 2; ++ri) {
        f32x4 hv = *(const f32x4*)&hst[i * 36 + ri * 16 + kgrp * 4];
        if (ci & 1) pm[1][ri] += hv * acc[ri][ci];
        else        pm[0][ri] += hv * acc[ri][ci];
      }
    }
  }
  {
    float* mw = &msw[w * 1056];
#pragma unroll
    for (int p = 0; p < 2; ++p) {
      int o = p * 16 + arow;
#pragma unroll
      for (int ri = 0; ri < 2; ++ri) {
        int rb = ri * 16 + kgrp * 4;
        mw[o * 33 + rb + 0] = pm[p][ri][0];
        mw[o * 33 + rb + 1] = pm[p][ri][1];
        mw[o * 33 + rb + 2] = pm[p][ri][2];
        mw[o * 33 + rb + 3] = pm[p][ri][3];
      }
    }
  }
  __syncthreads();
  {
    int row = t >> 3, o0 = (t & 7) * 4;
    int e = e0 + row;
    int sn = src_s[e];
    float4 hv = *(const float4*)&hc[(size_t)sn * 32 + o0];
    float vs[4];
#pragma unroll
    for (int j = 0; j < 4; ++j) {
      int o = o0 + j;
      vs[j] = msw[0 * 1056 + o * 33 + row] + msw[1 * 1056 + o * 33 + row] +
              msw[2 * 1056 + o * 33 + row] + msw[3 * 1056 + o * 33 + row];
    }
    float4 ov = make_float4(vs[0] + hv.x, vs[1] + hv.y, vs[2] + hv.z, vs[3] + hv.w);
    *(float4*)&msg_buf[(size_t)e * 32 + o0] = ov;
  }
}

// ---- GRU cell with CSR gather of sorted msgs; fused next-layer hc ----
__global__ __launch_bounds__(256) void gru_kernel(const float* __restrict__ msg_buf,
                                                  const int* __restrict__ rowptr,
                                                  const float* __restrict__ h_in,
                                                  const float* __restrict__ Wih,
                                                  const float* __restrict__ Whh,
                                                  const float* __restrict__ bih,
                                                  const float* __restrict__ bhh,
                                                  float* __restrict__ h_out,
                                                  const float* __restrict__ c2p,
                                                  float* __restrict__ hc_out,
                                                  int do_next, int N) {
  __shared__ float WT[32 * 96], UT[32 * 96];
  __shared__ float c2l[1024];
  __shared__ float mrow[256];
  __shared__ float hnew[256];
  int t = threadIdx.x;
  for (int idx = t; idx < 96 * 32; idx += 256) {
    int j = idx / 32, i = idx % 32;
    WT[i * 96 + j] = Wih[idx];
    UT[i * 96 + j] = Whh[idx];
  }
  if (do_next)
    for (int i = t; i < 1024; i += 256) c2l[i] = c2p[i];
  __syncthreads();
  int gid = blockIdx.x * 256 + t;
  int n = gid >> 5, o = gid & 31;
  int k0 = rowptr[n], k1 = rowptr[n + 1];
  float msum = 0.f;
  for (int k = k0; k < k1; ++k) msum += msg_buf[(size_t)k * 32 + o];
  float inv = 1.f / fmaxf((float)(k1 - k0), 1.f);
  mrow[t] = msum * inv;
  __syncthreads();
  int nl = t >> 5;
  float air = 0.f, aiz = 0.f, ain = 0.f, ahr = 0.f, ahz = 0.f, ahn = 0.f;
#pragma unroll
  for (int i = 0; i < 32; ++i) {
    float mi = mrow[nl * 32 + i];
    float hi = h_in[(size_t)n * 32 + i];
    const float* w = &WT[i * 96 + o];
    const float* u = &UT[i * 96 + o];
    air += mi * w[0];  aiz += mi * w[32];  ain += mi * w[64];
    ahr += hi * u[0];  ahz += hi * u[32];  ahn += hi * u[64];
  }
  float r = 1.f / (1.f + expf(-(air + bih[o] + ahr + bhh[o])));
  float z = 1.f / (1.f + expf(-(aiz + bih[o + 32] + ahz + bhh[o + 32])));
  float ng = tanhf(ain + bih[o + 64] + r * (ahn + bhh[o + 64]));
  float hval = (1.f - z) * ng + z * h_in[(size_t)n * 32 + o];
  h_out[gid] = hval;
  if (do_next) {
    hnew[t] = hval;
    __syncthreads();
    float a = 0.f;
#pragma unroll
    for (int i = 0; i < 32; ++i) a += hnew[nl * 32 + i] * c2l[i * 32 + o];
    hc_out[gid] = a;
  }
}

extern "C" void kernel_launch(void* const* d_in, const int* in_sizes, int n_in,
                              void* d_out, int out_size, void* d_ws, size_t ws_size,
                              hipStream_t stream) {
  const float* x_node = (const float*)d_in[0];
  const float* x_edge = (const float*)d_in[1];
  const int* src = (const int*)d_in[2];
  const int* dst = (const int*)d_in[3];
  const float* bn_n_g = (const float*)d_in[4];
  const float* bn_n_b = (const float*)d_in[5];
  const float* node_W = (const float*)d_in[6];
  const float* node_b = (const float*)d_in[7];
  const float* bn_e_g = (const float*)d_in[8];
  const float* bn_e_b = (const float*)d_in[9];
  const float* edge_W = (const float*)d_in[10];
  const float* edge_b = (const float*)d_in[11];
  const float* en_W1 = (const float*)d_in[12];
  const float* en_b1 = (const float*)d_in[13];
  const float* en_bn1_g = (const float*)d_in[14];
  const float* en_bn1_b = (const float*)d_in[15];
  const float* en_W2 = (const float*)d_in[16];
  const float* en_b2 = (const float*)d_in[17];
  const float* en_bn2_g = (const float*)d_in[18];
  const float* en_bn2_b = (const float*)d_in[19];
  const float* gWih = (const float*)d_in[20];
  const float* gWhh = (const float*)d_in[21];
  const float* gbih = (const float*)d_in[22];
  const float* gbhh = (const float*)d_in[23];
  float* out = (float*)d_out;

  char* ws = (char*)d_ws;
  __half* Tt      = (__half*)(ws + 0);              // 25,600,000 (dst-sorted rows)
  float* tsq_part = (float*)(ws + 25600000);        // 16,777,216
  float* h_a      = (float*)(ws + 42377216);        //  2,560,000
  float* h_b      = (float*)(ws + 44937216);        //  2,560,000
  float* msg_buf  = (float*)(ws + 47497216);        // 12,800,000
  float* hc       = (float*)(ws + 60297216);        //  2,560,000
  int*   src_s    = (int*)(ws + 62857216);          //    400,000
  int*   inv_e    = (int*)(ws + 63257216);          //    400,000
  int*   rowptr   = (int*)(ws + 63657216);          //     80,064
  int*   cursor   = (int*)(ws + 63737280);          //     80,000
  float* zbase    = (float*)(ws + 63817280);        //    147,584 (36,896 f)
  float* deg   = zbase;                             // 20000
  float* S     = zbase + 20000;                     // 16384
  float* tsum  = zbase + 36384;                     // 128
  float* sxs   = zbase + 36512;
  float* nstat = zbase + 36640;
  float* estat = zbase + 36768;
  float* par   = (float*)(ws + 63964864);           // 4096 f
  float* ns = par + 0;    float* nc = par + 64;
  float* es = par + 128;  float* ec = par + 192;
  float* s1 = par + 256;  float* c1 = par + 384;
  float* wc = par + 512;                            // 1280 f
  float* bcb = par + 1792;                          // 128 f
  float* s2 = par + 1920; float* c2p = par + 2944;  // 1024 f each
  unsigned short* Bp = (unsigned short*)(ws + 63981248);  // 262,144 B

  pre0<<<156, 256, 0, stream>>>(zbase, edge_W, edge_b, en_W1, en_b1, wc, bcb);
  pre1<<<450 + 391, 256, 0, stream>>>(x_node, x_edge, dst, nstat, estat, deg);
  pre2<<<3, 256, 0, stream>>>(nstat, estat, bn_n_g, bn_n_b, bn_e_g, bn_e_b,
                              ns, nc, es, ec, deg, rowptr, cursor);
  pre3<<<391 + 2500 + 391, 256, 0, stream>>>(x_edge, es, ec, sxs, x_node, ns, nc,
                                             node_W, node_b, h_a, src, dst,
                                             cursor, inv_e, src_s);
  bn1_from_sx<<<1, 128, 0, stream>>>(sxs, wc, bcb, en_bn1_g, en_bn1_b, s1, c1);
  t_kernel<<<NE / 16, 256, 0, stream>>>(x_edge, es, ec, wc, bcb, s1, c1, inv_e, Tt, NE);
  pre6<<<512 + TSQ_NB, 256, 0, stream>>>(Tt, tsum, tsq_part, NE);
  tsq_reduce<<<64, 256, 0, stream>>>(tsq_part, S);
  bn2p<<<256, 256, 0, stream>>>(S, tsum, en_W2, en_b2, en_bn2_g, en_bn2_b, s2, c2p);
  pre9<<<64 + 2500, 256, 0, stream>>>(en_W2, s2, Bp, h_a, c2p, hc);

  const float* hin = h_a;
  for (int l = 0; l < 3; ++l) {
    float* hout = (l == 0) ? h_b : (l == 1) ? h_a : out;
    msg_mfma<<<NE / 32, 256, 0, stream>>>(Tt, Bp, hin, hc, src_s, msg_buf, NE);
    gru_kernel<<<(NN * 32) / 256, 256, 0, stream>>>(msg_buf, rowptr, hin, gWih, gWhh,
                                                    gbih, gbhh, hout, c2p, hc,
                                                    (l < 2) ? 1 : 0, NN);
    hin = hout;
  }
}